// Round 10
// baseline (194.371 us; speedup 1.0000x reference)
//
#include <hip/hip_runtime.h>

typedef _Float16 half8 __attribute__((ext_vector_type(8)));
typedef _Float16 half4 __attribute__((ext_vector_type(4)));
typedef float    f32x4 __attribute__((ext_vector_type(4)));
typedef unsigned long long u64;

#define B_ 16
#define C_ 256
#define N_ 4096
#define TAU 0.02f

// f16 index into one [n=128][i=256] plane; 16B-granule XOR swizzle: G = (i>>3) ^ (n&7).
// MFMA b128 reads (i-run of 8, n per-lane): 2-way banks (free). Writes 8-way but only 8/thread.
#define XI(n, i) ( ((n) << 8) | (((((i) >> 3) ^ ((n) & 7)) & 31) << 3) | ((i) & 7) )

__device__ __forceinline__ u64 shfl_xor_u64(u64 v, int m) {
    unsigned lo = __shfl_xor((unsigned)v, m);
    unsigned hi = __shfl_xor((unsigned)(v >> 32), m);
    return ((u64)hi << 32) | lo;
}
// merge top-2 B into A (packed keys: higher = better; ~n low 32 gives first-index tie rule)
__device__ __forceinline__ void t2m(u64& A1, u64& A2, u64 B1, u64 B2) {
    bool aw = A1 > B1;
    u64 T1 = aw ? A1 : B1;
    u64 lv = aw ? B1 : A1;
    u64 wv = aw ? A2 : B2;
    A2 = lv > wv ? lv : wv;
    A1 = T1;
}
__device__ __forceinline__ float unkey(unsigned key) {
    unsigned u = (key & 0x80000000u) ? (key ^ 0x80000000u) : ~key;
    return __uint_as_float(u);
}

// ---------- prep: W' = 16*W -> f16 hi/lo, A-fragment-major ----------
// f16 index: ((cb*8+s)*64 + l)*8 + j ;  c = cb*16+(l&15), i = s*32+(l>>4)*8+j
__global__ void prep_w(const float* __restrict__ W,
                       _Float16* __restrict__ WfH, _Float16* __restrict__ WfL) {
    int t = blockIdx.x * 256 + threadIdx.x;  // 0..8191
    int l = t & 63, g = t >> 6;
    int s = g & 7, cb = g >> 3;
    int c = cb * 16 + (l & 15);
    int i0 = s * 32 + (l >> 4) * 8;
    int base = ((cb * 8 + s) * 64 + l) * 8;
#pragma unroll
    for (int j = 0; j < 8; ++j) {
        float w = 16.0f * W[c * C_ + i0 + j];
        _Float16 h  = (_Float16)w;
        _Float16 lo = (_Float16)(w - (float)h);
        WfH[base + j] = h;
        WfL[base + j] = lo;
    }
}

// ---------- main: k-outer, 128-n window (512B segments), dbuf k-planes ----------
// grid: 16 b * 32 n-windows; 1024 thr = 16 waves; wave w owns c[16w,16w+16) x 128 n.
__global__ __launch_bounds__(1024) void vn_main(
    const float* __restrict__ x,
    const _Float16* __restrict__ WfH, const _Float16* __restrict__ WfL,
    ulonglong2* __restrict__ btop)
{
    __shared__ __align__(16) _Float16 X[2][128 * 256];   // 2 x 64 KB k-planes

    const int tid  = threadIdx.x;
    const int lane = tid & 63;
    const int wid  = tid >> 6;          // 0..15 : 16-c block
    const int b    = blockIdx.x >> 5;
    const int nb   = blockIdx.x & 31;
    const int n0   = nb << 7;           // 128-n window
    const int g    = lane >> 4;
    const int t16  = lane & 15;

    const float* xb = x + ((size_t)(b * 768) << 12);

    // stage mapping: 32-thread group covers one i-quad row-set; lane nl covers 4 n (f32x4)
    const int nl = tid & 31;
    const int qb = tid >> 5;            // 0..31 (task half T adds 32)

    f32x4 vs[4];

#define SLOAD(T, K)  do { int i0_ = ((qb) + (T) * 32) << 2;                        \
    _Pragma("unroll") for (int r = 0; r < 4; ++r)                                  \
        vs[r] = *(const f32x4*)(xb + (((i0_ + r) * 3 + (K)) << 12) + n0 + (nl << 2)); \
    } while (0)

#define SWRITE(T, BUF) do { int i0_ = ((qb) + (T) * 32) << 2; int n4_ = nl << 2;   \
    _Pragma("unroll") for (int j = 0; j < 4; ++j) {                                \
        half4 h; h[0] = (_Float16)vs[0][j]; h[1] = (_Float16)vs[1][j];             \
        h[2] = (_Float16)vs[2][j]; h[3] = (_Float16)vs[3][j];                      \
        *(half4*)(&X[BUF][XI(n4_ + j, i0_)]) = h; }                                \
    } while (0)

#define WOFF(S) ((((wid << 3) + (S)) * 64 + lane) << 3)

    half8 ah[2], al;

    // prologue: stage k=0 -> buf0; W slice-0 frags
    ah[0] = *(const half8*)(WfH + WOFF(0));
    al    = *(const half8*)(WfL + WOFF(0));
    SLOAD(0, 0); SWRITE(0, 0);
    SLOAD(1, 0); SWRITE(1, 0);
    __syncthreads();

    f32x4 dp[8];
#pragma unroll
    for (int nf = 0; nf < 8; ++nf) dp[nf] = (f32x4){0.f, 0.f, 0.f, 0.f};

#pragma unroll
    for (int k = 0; k < 3; ++k) {
        const int bk = k & 1;
        f32x4 acc[8];
#pragma unroll
        for (int nf = 0; nf < 8; ++nf) acc[nf] = (f32x4){0.f, 0.f, 0.f, 0.f};

        if (k < 2) SLOAD(0, k + 1);      // 4 loads in flight across slices 0..3

#pragma unroll
        for (int s = 0; s < 8; ++s) {
            const int P = s & 1;
            if (s < 7) ah[P ^ 1] = *(const half8*)(WfH + WOFF(s + 1));
#pragma unroll
            for (int nf = 0; nf < 8; ++nf) {
                const half8 bh = *(const half8*)(&X[bk][XI(t16 + (nf << 4), (s << 5) + (g << 3))]);
                acc[nf] = __builtin_amdgcn_mfma_f32_16x16x32_f16(ah[P], bh, acc[nf], 0, 0, 0);
                acc[nf] = __builtin_amdgcn_mfma_f32_16x16x32_f16(al,    bh, acc[nf], 0, 0, 0);
            }
            if (s < 7) al = *(const half8*)(WfL + WOFF(s + 1));
            if (s == 3 && k < 2) { SWRITE(0, bk ^ 1); SLOAD(1, k + 1); }
        }

        // dp += x_k (f16, from LDS, C-frag layout) * d_k
#pragma unroll
        for (int nf = 0; nf < 8; ++nf) {
            const half4 xr = *(const half4*)(&X[bk][XI(t16 + (nf << 4), (wid << 4) + (g << 2))]);
#pragma unroll
            for (int r = 0; r < 4; ++r)
                dp[nf][r] += (float)xr[r] * acc[nf][r];
        }

        if (k < 2) {
            SWRITE(1, bk ^ 1);
            ah[0] = *(const half8*)(WfH + WOFF(0));   // reload slice-0 frags for next k
            al    = *(const half8*)(WfL + WOFF(0));
        }
        __syncthreads();
    }

    // ---- epilogue: pack keys, top-2 per 32-n window (4 per block), store ----
    const int cr = (wid << 4) + (g << 2);
#pragma unroll
    for (int r = 0; r < 4; ++r) {
#pragma unroll
        for (int w = 0; w < 4; ++w) {
            float d0 = dp[2 * w][r]     * 0.0625f;
            float d1 = dp[2 * w + 1][r] * 0.0625f;
            unsigned u0 = __float_as_uint(d0);
            unsigned k0 = (u0 & 0x80000000u) ? ~u0 : (u0 | 0x80000000u);
            unsigned u1 = __float_as_uint(d1);
            unsigned k1 = (u1 & 0x80000000u) ? ~u1 : (u1 | 0x80000000u);
            int nA = n0 + (w << 5) + t16;
            int nB = nA + 16;
            u64 A1 = ((u64)k0 << 32) | (unsigned)(~nA);
            u64 A2 = 0;
            u64 B1 = ((u64)k1 << 32) | (unsigned)(~nB);
            t2m(A1, A2, B1, 0);
#pragma unroll
            for (int m = 1; m <= 8; m <<= 1) {
                u64 C1 = shfl_xor_u64(A1, m);
                u64 C2 = shfl_xor_u64(A2, m);
                t2m(A1, A2, C1, C2);
            }
            if (t16 == 0) {
                int c = cr + r;
                btop[(size_t)((b << 8) + c) * 128 + (nb << 2) + w] = make_ulonglong2(A1, A2);
            }
        }
    }
}

// ---------- phase2: merge 128 windows, certify or exact-recompute, gather ----------
__global__ void phase2(const float* __restrict__ x, const float* __restrict__ W,
                       const ulonglong2* __restrict__ btop, float* __restrict__ out)
{
    const int bc = blockIdx.x;
    const int b = bc >> 8, c = bc & 255;
    const int lane = threadIdx.x;

    u64 A1 = 0, A2 = 0;
    u64 e1[2];
#pragma unroll
    for (int t = 0; t < 2; ++t) {
        ulonglong2 e = btop[(size_t)bc * 128 + t * 64 + lane];
        e1[t] = e.x;
        t2m(A1, A2, e.x, e.y);
    }
#pragma unroll
    for (int m = 1; m <= 32; m <<= 1) {
        u64 B1 = shfl_xor_u64(A1, m);
        u64 B2 = shfl_xor_u64(A2, m);
        t2m(A1, A2, B1, B2);
    }
    float v1 = unkey((unsigned)(A1 >> 32));
    float v2 = unkey((unsigned)(A2 >> 32));
    int winner = (int)(~(unsigned)A1) & (N_ - 1);

    if (!(v1 - v2 > TAU)) {
        float bv = -3.4e38f; int bi = 0x7fffffff;
#pragma unroll
        for (int t = 0; t < 2; ++t) {
            bool flag = unkey((unsigned)(e1[t] >> 32)) >= v1 - TAU;
            unsigned long long mask = __ballot(flag);
            while (mask) {
                int src = __builtin_ctzll(mask);
                mask &= mask - 1;
                int win = t * 64 + src;       // 32-n window
                for (int ch = 0; ch < 4; ++ch) {
                    int nbase = win * 32 + ch * 8;
                    float accv[8];
#pragma unroll
                    for (int m2 = 0; m2 < 8; ++m2) accv[m2] = 0.f;
                    float xc[3][8];
#pragma unroll
                    for (int k = 0; k < 3; ++k) {
                        const float* p = x + (((size_t)bc * 3 + k) << 12) + nbase;
#pragma unroll
                        for (int m2 = 0; m2 < 8; ++m2) xc[k][m2] = p[m2];
                    }
                    for (int q = 0; q < 4; ++q) {
                        int i = lane + (q << 6);
                        float wq = W[c * C_ + i];
#pragma unroll
                        for (int k = 0; k < 3; ++k) {
                            const float* p = x + ((((size_t)b * C_ + i) * 3 + k) << 12) + nbase;
#pragma unroll
                            for (int m2 = 0; m2 < 8; ++m2)
                                accv[m2] += wq * p[m2] * xc[k][m2];
                        }
                    }
#pragma unroll
                    for (int m2 = 0; m2 < 8; ++m2) {
#pragma unroll
                        for (int mm = 1; mm <= 32; mm <<= 1)
                            accv[m2] += __shfl_xor(accv[m2], mm);
                        int n = nbase + m2;
                        if (accv[m2] > bv || (accv[m2] == bv && n < bi)) { bv = accv[m2]; bi = n; }
                    }
                }
            }
        }
        winner = bi;
    }

    if (lane < 3)
        out[bc * 3 + lane] = x[(((size_t)bc * 3 + lane) << 12) + winner];
}

extern "C" void kernel_launch(void* const* d_in, const int* in_sizes, int n_in,
                              void* d_out, int out_size, void* d_ws, size_t ws_size,
                              hipStream_t stream) {
    const float* x = (const float*)d_in[0];
    const float* W = (const float*)d_in[1];
    float* out = (float*)d_out;

    _Float16*   WfH  = (_Float16*)d_ws;                      // 128 KB
    _Float16*   WfL  = (_Float16*)((char*)d_ws + 131072);    // 128 KB
    ulonglong2* btop = (ulonglong2*)((char*)d_ws + 262144);  // 8 MB: [bc][128] (K1,K2)

    prep_w<<<32, 256, 0, stream>>>(W, WfH, WfL);
    vn_main<<<B_ * 32, 1024, 0, stream>>>(x, WfH, WfL, btop);
    phase2<<<B_ * C_, 64, 0, stream>>>(x, W, btop, out);
}